// Round 8
// baseline (3065.555 us; speedup 1.0000x reference)
//
#include <hip/hip_runtime.h>

// Problem constants: N=512, BS=64, DIM=256, SIZE=8192
#define T_TOTAL 32768   // N*BS queries
#define D       256
#define K       8192
#define BQ      64      // queries per block tile (4 row-tiles of 16) — shared by all 8 waves
#define KSPLIT  4
#define KSLICE  (K / KSPLIT)
#define NSLICE  (KSPLIT * 4)        // (slice, wn<4) pairs write disjoint partial slices
#define NCT     (K / 16)            // 512 code-tiles
#define KT_STRIDE (NCT * 64 * 8)    // halves per kt plane = 262144
#define NQB     (T_TOTAL / BQ)      // 512 query-blocks

typedef _Float16 half4f  __attribute__((ext_vector_type(4)));
typedef _Float16 half8f  __attribute__((ext_vector_type(8)));
typedef float    floatx4 __attribute__((ext_vector_type(4)));

// d_out scratch: Bhi/Blo after the first PARTIAL_F floats. If ws is big enough,
// partial lives in ws (enables fused reduce+gather); else at d_out head (R12 path).
#define PARTIAL_F 1048576
#define BHALVES   2097152   // halves per B array (8*512*64*8)

__device__ __forceinline__ _Float16 hi16(float x) { return (_Float16)x; }
__device__ __forceinline__ _Float16 lo16(float x, _Float16 h) { return (_Float16)(x - (float)h); }
__device__ __forceinline__ void split4(float4 v, half4f& h, half4f& l) {
    _Float16 hx = hi16(v.x), hy = hi16(v.y), hz = hi16(v.z), hw = hi16(v.w);
    h = (half4f){hx, hy, hz, hw};
    l = (half4f){lo16(v.x, hx), lo16(v.y, hy), lo16(v.z, hz), lo16(v.w, hw)};
}

// ---- kernel 1: fused vocab prep: hv2 (fp32-exact) + fp16 hi/lo fragment-order split ----
// 512 blocks, one 16-code tile each. Wave w handles codes 4w..4w+3 (lane = k4 along D).
__global__ void prep_kernel(const float* __restrict__ vocab,
                            _Float16* __restrict__ bhi, _Float16* __restrict__ blo,
                            float* __restrict__ hv2) {
    const int ct = blockIdx.x;
    const int t  = threadIdx.x;
    const int k4 = t & 63;               // float4 index along D
    const int w  = t >> 6;
    const float4* voc4 = (const float4*)vocab;
    const int kt = k4 >> 3, kg = (k4 >> 1) & 3, h = k4 & 1;
    float ss[4];
    #pragma unroll
    for (int ci = 0; ci < 4; ++ci) {
        int cc = w * 4 + ci;             // code within tile
        float4 v = voc4[(size_t)(ct * 16 + cc) * (D / 4) + k4];
        half4f hh, ll;
        split4(v, hh, ll);
        size_t off = (((size_t)kt * NCT + ct) * 64 + (cc + 16 * kg)) * 8 + h * 4;
        *(half4f*)&bhi[off] = hh;
        *(half4f*)&blo[off] = ll;
        ss[ci] = v.x * v.x + v.y * v.y + v.z * v.z + v.w * v.w;
    }
    #pragma unroll
    for (int ci = 0; ci < 4; ++ci) {
        float s = ss[ci];
        #pragma unroll
        for (int off = 32; off; off >>= 1) s += __shfl_down(s, off, 64);
        if ((t & 63) == 0) hv2[ct * 16 + w * 4 + ci] = 0.5f * s;
    }
}

// ------ kernel 2: MFMA argmin; 3-term split; 8 code-split waves + B depth-1 ping-pong ----
// R6 result: 4 waves/SIMD alone left MfmaUtil at 60% — waves stay LOCKSTEPPED (pipe
// round-robin -> all bursts end together -> all waves stall in the same vmcnt wait).
// R7 added B ping-pong but had a stride bug (cb += 4096; correct is 8192: one c0 tile
// = 16 code-tiles x 512 halves) -> wrong codes from c0i=1 on. R8 = R7 + stride fix.
// B loads issue one full 24-MFMA burst (~490cy >= L2 latency) before use, continuous
// across c0i boundaries. A stays in-body (LDS latency, covered by other waves).
// Register budget <=128: acc 32 + B 2x16 + A 32 transient + best 16 + bidxp 8 + misc.
__attribute__((amdgpu_flat_work_group_size(512, 512), amdgpu_waves_per_eu(4)))
__global__ void argmin_kernel(const float* __restrict__ seq,
                              const _Float16* __restrict__ bhi,
                              const _Float16* __restrict__ blo,
                              const float* __restrict__ hv2,
                              float2* __restrict__ partial) {
    // A LDS in fragment order [rt 0..3][kt 0..7][flane 0..63][8], XOR-swizzled by kt<<3
    __shared__ _Float16 AhL[4 * 8 * 64 * 8];   // 32 KB
    __shared__ _Float16 AlL[4 * 8 * 64 * 8];   // 32 KB

    const int t    = threadIdx.x;
    const int lane = t & 63;
    const int wn   = t >> 6;            // code octant 0..7 (32 codes each per c0 tile)
    const int bi   = blockIdx.x;
    const int slice = (bi & 7) >> 1;    // 0..3  (XCD-locked K-slice)
    const int qb    = (bi >> 3) * 2 + (bi & 1);  // 0..511
    const int q0   = qb * BQ;
    const int k0   = slice * KSLICE;

    const float4* seq4 = (const float4*)seq;

    // ---- prologue: split A (64 rows x 256 dims) into fragment-order LDS, once ----
    #pragma unroll
    for (int i = 0; i < 8; ++i) {
        int f   = t + 512 * i;          // 0..4095 float4s
        int row = f >> 6;               // 0..63
        int d4  = f & 63;               // float4 along D
        float4 v = seq4[(size_t)(q0 + row) * (D / 4) + d4];
        half4f h, l;
        split4(v, h, l);
        int kt = d4 >> 3, kg = (d4 >> 1) & 3, hh = d4 & 1;
        int off = (((((row >> 4) * 8 + kt) * 64) + ((row & 15) + 16 * kg)) * 8 + hh * 4)
                  ^ (kt << 3);          // swizzle: write conflicts 32-way -> 4-way
        *(half4f*)&AhL[off] = h;
        *(half4f*)&AlL[off] = l;
    }
    __syncthreads();

    float    best[16];
    unsigned bidxp[8];                  // 2x16-bit packed indices (K fits in 13 bits)
    #pragma unroll
    for (int b = 0; b < 16; ++b) best[b] = 3.4e38f;
    #pragma unroll
    for (int b = 0; b < 8; ++b) bidxp[b] = 0u;

    const _Float16* bh_l = bhi + (size_t)lane * 8;
    const _Float16* bl_l = blo + (size_t)lane * 8;

    // B prefetch: plane X of 16-dim slabs at tile base CB (halves)
#define PF_B(BH, BL, CB, X) do {                                               \
        const size_t kb_ = (size_t)(X) * KT_STRIDE + (CB);                     \
        BH[0] = *(const half8f*)&bh_l[kb_];                                    \
        BH[1] = *(const half8f*)&bh_l[kb_ + 512];                              \
        BL[0] = *(const half8f*)&bl_l[kb_];                                    \
        BL[1] = *(const half8f*)&bl_l[kb_ + 512];                              \
    } while (0)

    // 24 MFMAs, term-outer (8 independent accs between dependent same-acc pairs);
    // al consumed only by term 1 (short liveness), ah by terms 2-3.
#define BURST(AH, AL, BH, BL) do {                                                               \
        __builtin_amdgcn_s_setprio(1);                                                           \
        _Pragma("unroll")                                                                        \
        for (int nj = 0; nj < 2; ++nj)                                                           \
            _Pragma("unroll")                                                                    \
            for (int mi = 0; mi < 4; ++mi)                                                       \
                acc[mi][nj] = __builtin_amdgcn_mfma_f32_16x16x32_f16(AL[mi], BH[nj], acc[mi][nj], 0, 0, 0); \
        _Pragma("unroll")                                                                        \
        for (int nj = 0; nj < 2; ++nj)                                                           \
            _Pragma("unroll")                                                                    \
            for (int mi = 0; mi < 4; ++mi)                                                       \
                acc[mi][nj] = __builtin_amdgcn_mfma_f32_16x16x32_f16(AH[mi], BL[nj], acc[mi][nj], 0, 0, 0); \
        _Pragma("unroll")                                                                        \
        for (int nj = 0; nj < 2; ++nj)                                                           \
            _Pragma("unroll")                                                                    \
            for (int mi = 0; mi < 4; ++mi)                                                       \
                acc[mi][nj] = __builtin_amdgcn_mfma_f32_16x16x32_f16(AH[mi], BH[nj], acc[mi][nj], 0, 0, 0); \
        __builtin_amdgcn_s_setprio(0);                                                           \
    } while (0)

#define LOAD_A(AH, AL, X) do {                                                 \
        _Pragma("unroll")                                                      \
        for (int mi = 0; mi < 4; ++mi) {                                       \
            const int ao_ = (((mi * 8 + (X)) * 64 + lane) * 8) ^ ((X) << 3);   \
            AL[mi] = *(const half8f*)&AlL[ao_];                                \
            AH[mi] = *(const half8f*)&AhL[ao_];                                \
        }                                                                      \
    } while (0)

    half8f bh0[2], bl0[2], bh1[2], bl1[2];

    // c0 tile stride in halves: 16 code-tiles x 512 = 8192 (R7 bug: used 4096)
    size_t cb = ((size_t)(k0 >> 4) + wn * 2) * 512;   // c0i=0 tile base (halves)
    PF_B(bh0, bl0, cb, 0);              // prime the pipeline

    for (int c0i = 0; c0i < KSLICE / 256; ++c0i) {   // 8 c0 tiles of 256 codes
        const int c0 = k0 + c0i * 256;

        // hv2 for the epilogue: issued here, consumed ~8 kt later (fully hidden)
        const float hvv0 = hv2[c0 + (wn * 2 + 0) * 16 + (lane & 15)];
        const float hvv1 = hv2[c0 + (wn * 2 + 1) * 16 + (lane & 15)];

        floatx4 acc[4][2];
        #pragma unroll
        for (int mi = 0; mi < 4; ++mi)
            #pragma unroll
            for (int nj = 0; nj < 2; ++nj) acc[mi][nj] = (floatx4){0.f, 0.f, 0.f, 0.f};

        #pragma unroll 1   // REAL loop: bounded hoist window (anti-spill)
        for (int kt2 = 0; kt2 < 4; ++kt2) {
            const int kt = kt2 * 2;
            // prefetch B(kt+1) -> buf1; consumed after burst(kt) (~490cy cover)
            PF_B(bh1, bl1, cb, kt + 1);
            // A(kt) in-body: 8 ds_reads, first use ~150cy later (other waves cover)
            half8f ah[4], al[4];
            LOAD_A(ah, al, kt);
            BURST(ah, al, bh0, bl0);
            // prefetch B(kt+2) -> buf0; on the last lap, next tile's plane 0.
            // Bounds: max in-loop addr = 7*KT_STRIDE + 261120 + 512 + 63*8 + 8
            // = 2097152 = BHALVES (16B read ends exactly at the boundary);
            // final-lap cross-tile prefetch tops out at 270336 << BHALVES.
            if (kt2 < 3) PF_B(bh0, bl0, cb, kt + 2);
            else         PF_B(bh0, bl0, cb + 8192, 0);
            half8f ah1[4], al1[4];
            LOAD_A(ah1, al1, kt + 1);
            BURST(ah1, al1, bh1, bl1);
        }
        cb += 8192;   // 16 code-tiles x 512 halves per c0 tile (the R7 fix)

        // epilogue: s = 0.5*|v|^2 - dot; running first-argmin (ascending c per lane).
        // C/D layout: col = lane&15, row = (lane>>4)*4 + reg
        #pragma unroll
        for (int nj = 0; nj < 2; ++nj) {
            const int c = c0 + (wn * 2 + nj) * 16 + (lane & 15);
            const float hv = nj ? hvv1 : hvv0;
            const unsigned clo = (unsigned)c;
            const unsigned chi = (unsigned)c << 16;
            #pragma unroll
            for (int mi = 0; mi < 4; ++mi)
                #pragma unroll
                for (int r = 0; r < 4; r += 2) {
                    const int b = mi * 4 + r;
                    float s0 = hv - acc[mi][nj][r];
                    float s1 = hv - acc[mi][nj][r + 1];
                    unsigned w = bidxp[b >> 1];
                    if (s0 < best[b])     { best[b] = s0;     w = (w & 0xFFFF0000u) | clo; }
                    if (s1 < best[b + 1]) { best[b + 1] = s1; w = (w & 0x0000FFFFu) | chi; }
                    bidxp[b >> 1] = w;
                }
        }
    }
#undef PF_B
#undef BURST
#undef LOAD_A

    // unpack indices (registers are cheap after the hot loop)
    int bidx[16];
    #pragma unroll
    for (int b = 0; b < 16; ++b)
        bidx[b] = (b & 1) ? (int)(bidxp[b >> 1] >> 16) : (int)(bidxp[b >> 1] & 0xFFFFu);

    // reduce across the 16 col-lanes (same rows, 16 different cols)
    #pragma unroll
    for (int off = 1; off < 16; off <<= 1) {
        #pragma unroll
        for (int b = 0; b < 16; ++b) {
            float ob = __shfl_xor(best[b], off, 64);
            int   oi = __shfl_xor(bidx[b], off, 64);
            if (ob < best[b] || (ob == best[b] && oi < bidx[b])) {
                best[b] = ob; bidx[b] = oi;
            }
        }
    }

    // fold waves wn>=4 into wn<4 via (now dead) A-LDS, keeping NSLICE=16
    float2* fold = (float2*)AhL;        // 4 waves x 64 rows x float2 = 2 KB
    __syncthreads();                    // everyone done reading A
    if (wn >= 4 && (lane & 15) == 0) {
        #pragma unroll
        for (int mi = 0; mi < 4; ++mi)
            #pragma unroll
            for (int r = 0; r < 4; ++r) {
                int row = mi * 16 + (lane >> 4) * 4 + r;
                fold[(wn - 4) * 64 + row] =
                    make_float2(best[mi * 4 + r], (float)bidx[mi * 4 + r]);
            }
    }
    __syncthreads();
    if (wn < 4 && (lane & 15) == 0) {
        const size_t sl = (size_t)(slice * 4 + wn) * T_TOTAL;  // disjoint per (slice, wn)
        #pragma unroll
        for (int mi = 0; mi < 4; ++mi)
            #pragma unroll
            for (int r = 0; r < 4; ++r) {
                int row = mi * 16 + (lane >> 4) * 4 + r;
                int b = mi * 4 + r;
                float2 p = fold[wn * 64 + row];
                int pi = (int)p.y;
                if (p.x < best[b] || (p.x == best[b] && pi < bidx[b])) {
                    best[b] = p.x; bidx[b] = pi;
                }
                partial[sl + q0 + row] = make_float2(best[b], (float)bidx[b]);
            }
    }
}

// ---- kernel 3a (fused, needs partial in ws): fold 16 slices + gather, wave per row ----
__global__ void redgather_kernel(const float* __restrict__ vocab,
                                 const float2* __restrict__ partial,
                                 float* __restrict__ out) {
    int r    = blockIdx.x * 4 + (threadIdx.x >> 6);
    int lane = threadIdx.x & 63;
    float bm = 3.4e38f;
    int   bi = 0x7fffffff;
    if (lane < 16) {
        float2 p = partial[(size_t)lane * T_TOTAL + r];
        bm = p.x; bi = (int)p.y;
    }
    #pragma unroll
    for (int off = 1; off < 16; off <<= 1) {   // xor<16 stays within the 16-lane group
        float ob = __shfl_xor(bm, off, 64);
        int   oi = __shfl_xor(bi, off, 64);
        if (ob < bm || (ob == bm && oi < bi)) { bm = ob; bi = oi; }
    }
    int k = __shfl(bi, 0, 64);                 // lanes 0-15 hold the true min; take lane 0
    const float4* src = (const float4*)(vocab + (size_t)k * D);
    float4*       dst = (float4*)(out + (size_t)r * D);
    dst[lane] = src[lane];
    if (lane == 0) out[(size_t)T_TOTAL * D + r] = (float)k;
}

// ---- kernel 3b/4b (fallback path, partial at d_out head): separate reduce + gather ----
__global__ void reduce_kernel(const float2* __restrict__ partial, int* __restrict__ idx) {
    int q = blockIdx.x * 256 + threadIdx.x;
    float bm = 3.4e38f;
    int   bi = 0x7fffffff;
    #pragma unroll
    for (int s = 0; s < NSLICE; ++s) {
        float2 p = partial[(size_t)s * T_TOTAL + q];
        int pi = (int)p.y;
        if (p.x < bm || (p.x == bm && pi < bi)) { bm = p.x; bi = pi; }
    }
    idx[q] = bi;
}

__global__ void gather_kernel(const float* __restrict__ vocab,
                              const int* __restrict__ idx,
                              float* __restrict__ out) {
    int r    = blockIdx.x * 4 + (threadIdx.x >> 6);
    int lane = threadIdx.x & 63;
    int k = idx[r];
    const float4* src = (const float4*)(vocab + (size_t)k * D);
    float4*       dst = (float4*)(out + (size_t)r * D);
    dst[lane] = src[lane];
    if (lane == 0) out[(size_t)T_TOTAL * D + r] = (float)k;
}

extern "C" void kernel_launch(void* const* d_in, const int* in_sizes, int n_in,
                              void* d_out, int out_size, void* d_ws, size_t ws_size,
                              hipStream_t stream) {
    const float* seq   = (const float*)d_in[0];   // [T, D] f32
    const float* vocab = (const float*)d_in[1];   // [K, D] f32
    float* out = (float*)d_out;

    float* hv2 = (float*)d_ws;                               // K floats
    _Float16* bhi = (_Float16*)(out + PARTIAL_F);            // 4 MB (d_out scratch)
    _Float16* blo = bhi + BHALVES;                           // 4 MB

    // partial placement: ws if it fits (enables fused reduce+gather — no cross-kernel
    // race since gather never writes ws), else d_out head (R12 2-kernel path).
    const size_t need_ws = (size_t)(K + 2 * NSLICE * T_TOTAL) * sizeof(float) + 256;
    const bool fused = ws_size >= need_ws;

    hipLaunchKernelGGL(prep_kernel, dim3(NCT), dim3(256), 0, stream, vocab, bhi, blo, hv2);

    if (fused) {
        float2* partial = (float2*)(hv2 + K);                // in ws
        hipLaunchKernelGGL(argmin_kernel,    dim3(NQB * KSPLIT), dim3(512), 0, stream,
                           seq, bhi, blo, hv2, partial);
        hipLaunchKernelGGL(redgather_kernel, dim3(T_TOTAL / 4),  dim3(256), 0, stream,
                           vocab, partial, out);
    } else {
        float2* partial = (float2*)d_out;                    // at d_out head
        int* idx = (int*)(hv2 + K);                          // T ints in ws
        hipLaunchKernelGGL(argmin_kernel, dim3(NQB * KSPLIT), dim3(512), 0, stream,
                           seq, bhi, blo, hv2, partial);
        hipLaunchKernelGGL(reduce_kernel, dim3(T_TOTAL / 256), dim3(256), 0, stream, partial, idx);
        hipLaunchKernelGGL(gather_kernel, dim3(T_TOTAL / 4),   dim3(256), 0, stream, vocab, idx, out);
    }
}

// Round 9
// 464.521 us; speedup vs baseline: 6.5994x; 6.5994x over previous
//
#include <hip/hip_runtime.h>

// Problem constants: N=512, BS=64, DIM=256, SIZE=8192
#define T_TOTAL 32768   // N*BS queries
#define D       256
#define K       8192
#define BQ      64      // queries per block tile (4 row-tiles of 16) — shared by all 8 waves
#define KSPLIT  4
#define KSLICE  (K / KSPLIT)
#define NSLICE  (KSPLIT * 4)        // (slice, wn<4) pairs write disjoint partial slices
#define NCT     (K / 16)            // 512 code-tiles
#define KT_STRIDE (NCT * 64 * 8)    // halves per kt plane = 262144
#define NQB     (T_TOTAL / BQ)      // 512 query-blocks

typedef _Float16 half4f  __attribute__((ext_vector_type(4)));
typedef _Float16 half8f  __attribute__((ext_vector_type(8)));
typedef float    floatx4 __attribute__((ext_vector_type(4)));

// d_out scratch: Bhi/Blo after the first PARTIAL_F floats. If ws is big enough,
// partial lives in ws (enables fused reduce+gather); else at d_out head (R12 path).
#define PARTIAL_F 1048576
#define BHALVES   2097152   // halves per B array (8*512*64*8)

__device__ __forceinline__ _Float16 hi16(float x) { return (_Float16)x; }
__device__ __forceinline__ _Float16 lo16(float x, _Float16 h) { return (_Float16)(x - (float)h); }
__device__ __forceinline__ void split4(float4 v, half4f& h, half4f& l) {
    _Float16 hx = hi16(v.x), hy = hi16(v.y), hz = hi16(v.z), hw = hi16(v.w);
    h = (half4f){hx, hy, hz, hw};
    l = (half4f){lo16(v.x, hx), lo16(v.y, hy), lo16(v.z, hz), lo16(v.w, hw)};
}

// ---- kernel 1: fused vocab prep: hv2 (fp32-exact) + fp16 hi/lo fragment-order split ----
// 512 blocks, one 16-code tile each. Wave w handles codes 4w..4w+3 (lane = k4 along D).
__global__ void prep_kernel(const float* __restrict__ vocab,
                            _Float16* __restrict__ bhi, _Float16* __restrict__ blo,
                            float* __restrict__ hv2) {
    const int ct = blockIdx.x;
    const int t  = threadIdx.x;
    const int k4 = t & 63;               // float4 index along D
    const int w  = t >> 6;
    const float4* voc4 = (const float4*)vocab;
    const int kt = k4 >> 3, kg = (k4 >> 1) & 3, h = k4 & 1;
    float ss[4];
    #pragma unroll
    for (int ci = 0; ci < 4; ++ci) {
        int cc = w * 4 + ci;             // code within tile
        float4 v = voc4[(size_t)(ct * 16 + cc) * (D / 4) + k4];
        half4f hh, ll;
        split4(v, hh, ll);
        size_t off = (((size_t)kt * NCT + ct) * 64 + (cc + 16 * kg)) * 8 + h * 4;
        *(half4f*)&bhi[off] = hh;
        *(half4f*)&blo[off] = ll;
        ss[ci] = v.x * v.x + v.y * v.y + v.z * v.z + v.w * v.w;
    }
    #pragma unroll
    for (int ci = 0; ci < 4; ++ci) {
        float s = ss[ci];
        #pragma unroll
        for (int off = 32; off; off >>= 1) s += __shfl_down(s, off, 64);
        if ((t & 63) == 0) hv2[ct * 16 + w * 4 + ci] = 0.5f * s;
    }
}

// ------ kernel 2: MFMA argmin; 3-term split; 8 code-split waves + B depth-1 ping-pong ----
// R6: 4 waves/SIMD, no prefetch -> lockstep vmcnt bubble, MfmaUtil 60%.
// R8: correct code (absmax 0) but amdgpu_waves_per_eu(4) let the backend target the
// 8-waves/EU 64-reg bucket -> ~60 hot regs spilled, 14 GB scratch traffic, 3 ms.
// R9 fix: __launch_bounds__(512, 2). 2nd arg is minBlocksPerMultiprocessor (HIP
// semantics; verified by R4: (512,4)->64-reg cap = 32 waves/CU): 2 blocks x 8 waves
// = 16 waves/CU -> 128-reg cap, demand-driven allocation (R0-R3 precedent: never
// voluntarily squeezed below demand under launch_bounds).
// Structure: B loads issue one full 24-MFMA burst (~490cy >= L2 latency) before use,
// continuous across c0i boundaries; A in-body (LDS latency covered by other waves).
__launch_bounds__(512, 2)
__global__ void argmin_kernel(const float* __restrict__ seq,
                              const _Float16* __restrict__ bhi,
                              const _Float16* __restrict__ blo,
                              const float* __restrict__ hv2,
                              float2* __restrict__ partial) {
    // A LDS in fragment order [rt 0..3][kt 0..7][flane 0..63][8], XOR-swizzled by kt<<3
    __shared__ _Float16 AhL[4 * 8 * 64 * 8];   // 32 KB
    __shared__ _Float16 AlL[4 * 8 * 64 * 8];   // 32 KB

    const int t    = threadIdx.x;
    const int lane = t & 63;
    const int wn   = t >> 6;            // code octant 0..7 (32 codes each per c0 tile)
    const int bi   = blockIdx.x;
    const int slice = (bi & 7) >> 1;    // 0..3  (XCD-locked K-slice)
    const int qb    = (bi >> 3) * 2 + (bi & 1);  // 0..511
    const int q0   = qb * BQ;
    const int k0   = slice * KSLICE;

    const float4* seq4 = (const float4*)seq;

    // ---- prologue: split A (64 rows x 256 dims) into fragment-order LDS, once ----
    #pragma unroll
    for (int i = 0; i < 8; ++i) {
        int f   = t + 512 * i;          // 0..4095 float4s
        int row = f >> 6;               // 0..63
        int d4  = f & 63;               // float4 along D
        float4 v = seq4[(size_t)(q0 + row) * (D / 4) + d4];
        half4f h, l;
        split4(v, h, l);
        int kt = d4 >> 3, kg = (d4 >> 1) & 3, hh = d4 & 1;
        int off = (((((row >> 4) * 8 + kt) * 64) + ((row & 15) + 16 * kg)) * 8 + hh * 4)
                  ^ (kt << 3);          // swizzle: write conflicts 32-way -> 4-way
        *(half4f*)&AhL[off] = h;
        *(half4f*)&AlL[off] = l;
    }
    __syncthreads();

    float    best[16];
    unsigned bidxp[8];                  // 2x16-bit packed indices (K fits in 13 bits)
    #pragma unroll
    for (int b = 0; b < 16; ++b) best[b] = 3.4e38f;
    #pragma unroll
    for (int b = 0; b < 8; ++b) bidxp[b] = 0u;

    const _Float16* bh_l = bhi + (size_t)lane * 8;
    const _Float16* bl_l = blo + (size_t)lane * 8;

    // B prefetch: plane X of 16-dim slabs at tile base CB (halves)
#define PF_B(BH, BL, CB, X) do {                                               \
        const size_t kb_ = (size_t)(X) * KT_STRIDE + (CB);                     \
        BH[0] = *(const half8f*)&bh_l[kb_];                                    \
        BH[1] = *(const half8f*)&bh_l[kb_ + 512];                              \
        BL[0] = *(const half8f*)&bl_l[kb_];                                    \
        BL[1] = *(const half8f*)&bl_l[kb_ + 512];                              \
    } while (0)

    // 24 MFMAs, term-outer (8 independent accs between dependent same-acc pairs);
    // al consumed only by term 1 (short liveness), ah by terms 2-3.
#define BURST(AH, AL, BH, BL) do {                                                               \
        __builtin_amdgcn_s_setprio(1);                                                           \
        _Pragma("unroll")                                                                        \
        for (int nj = 0; nj < 2; ++nj)                                                           \
            _Pragma("unroll")                                                                    \
            for (int mi = 0; mi < 4; ++mi)                                                       \
                acc[mi][nj] = __builtin_amdgcn_mfma_f32_16x16x32_f16(AL[mi], BH[nj], acc[mi][nj], 0, 0, 0); \
        _Pragma("unroll")                                                                        \
        for (int nj = 0; nj < 2; ++nj)                                                           \
            _Pragma("unroll")                                                                    \
            for (int mi = 0; mi < 4; ++mi)                                                       \
                acc[mi][nj] = __builtin_amdgcn_mfma_f32_16x16x32_f16(AH[mi], BL[nj], acc[mi][nj], 0, 0, 0); \
        _Pragma("unroll")                                                                        \
        for (int nj = 0; nj < 2; ++nj)                                                           \
            _Pragma("unroll")                                                                    \
            for (int mi = 0; mi < 4; ++mi)                                                       \
                acc[mi][nj] = __builtin_amdgcn_mfma_f32_16x16x32_f16(AH[mi], BH[nj], acc[mi][nj], 0, 0, 0); \
        __builtin_amdgcn_s_setprio(0);                                                           \
    } while (0)

#define LOAD_A(AH, AL, X) do {                                                 \
        _Pragma("unroll")                                                      \
        for (int mi = 0; mi < 4; ++mi) {                                       \
            const int ao_ = (((mi * 8 + (X)) * 64 + lane) * 8) ^ ((X) << 3);   \
            AL[mi] = *(const half8f*)&AlL[ao_];                                \
            AH[mi] = *(const half8f*)&AhL[ao_];                                \
        }                                                                      \
    } while (0)

    half8f bh0[2], bl0[2], bh1[2], bl1[2];

    // c0 tile stride in halves: 16 code-tiles x 512 = 8192 (R7's bug was 4096)
    size_t cb = ((size_t)(k0 >> 4) + wn * 2) * 512;   // c0i=0 tile base (halves)
    PF_B(bh0, bl0, cb, 0);              // prime the pipeline

    for (int c0i = 0; c0i < KSLICE / 256; ++c0i) {   // 8 c0 tiles of 256 codes
        const int c0 = k0 + c0i * 256;

        // hv2 for the epilogue: issued here, consumed ~8 kt later (fully hidden)
        const float hvv0 = hv2[c0 + (wn * 2 + 0) * 16 + (lane & 15)];
        const float hvv1 = hv2[c0 + (wn * 2 + 1) * 16 + (lane & 15)];

        floatx4 acc[4][2];
        #pragma unroll
        for (int mi = 0; mi < 4; ++mi)
            #pragma unroll
            for (int nj = 0; nj < 2; ++nj) acc[mi][nj] = (floatx4){0.f, 0.f, 0.f, 0.f};

        #pragma unroll 1   // REAL loop: bounded hoist window (anti-spill)
        for (int kt2 = 0; kt2 < 4; ++kt2) {
            const int kt = kt2 * 2;
            // prefetch B(kt+1) -> buf1; consumed after burst(kt) (~490cy cover)
            PF_B(bh1, bl1, cb, kt + 1);
            // A(kt) in-body: 8 ds_reads, first use ~150cy later (other waves cover)
            half8f ah[4], al[4];
            LOAD_A(ah, al, kt);
            BURST(ah, al, bh0, bl0);
            // prefetch B(kt+2) -> buf0; on the last lap, next tile's plane 0.
            // Bounds: max in-loop addr = 7*KT_STRIDE + 261120 + 512 + 63*8 + 8
            // = 2097152 = BHALVES (16B read ends exactly at the boundary);
            // final-lap cross-tile prefetch tops out at 270336 << BHALVES.
            if (kt2 < 3) PF_B(bh0, bl0, cb, kt + 2);
            else         PF_B(bh0, bl0, cb + 8192, 0);
            half8f ah1[4], al1[4];
            LOAD_A(ah1, al1, kt + 1);
            BURST(ah1, al1, bh1, bl1);
        }
        cb += 8192;   // 16 code-tiles x 512 halves per c0 tile

        // epilogue: s = 0.5*|v|^2 - dot; running first-argmin (ascending c per lane).
        // C/D layout: col = lane&15, row = (lane>>4)*4 + reg
        #pragma unroll
        for (int nj = 0; nj < 2; ++nj) {
            const int c = c0 + (wn * 2 + nj) * 16 + (lane & 15);
            const float hv = nj ? hvv1 : hvv0;
            const unsigned clo = (unsigned)c;
            const unsigned chi = (unsigned)c << 16;
            #pragma unroll
            for (int mi = 0; mi < 4; ++mi)
                #pragma unroll
                for (int r = 0; r < 4; r += 2) {
                    const int b = mi * 4 + r;
                    float s0 = hv - acc[mi][nj][r];
                    float s1 = hv - acc[mi][nj][r + 1];
                    unsigned w = bidxp[b >> 1];
                    if (s0 < best[b])     { best[b] = s0;     w = (w & 0xFFFF0000u) | clo; }
                    if (s1 < best[b + 1]) { best[b + 1] = s1; w = (w & 0x0000FFFFu) | chi; }
                    bidxp[b >> 1] = w;
                }
        }
    }
#undef PF_B
#undef BURST
#undef LOAD_A

    // unpack indices (registers are cheap after the hot loop)
    int bidx[16];
    #pragma unroll
    for (int b = 0; b < 16; ++b)
        bidx[b] = (b & 1) ? (int)(bidxp[b >> 1] >> 16) : (int)(bidxp[b >> 1] & 0xFFFFu);

    // reduce across the 16 col-lanes (same rows, 16 different cols)
    #pragma unroll
    for (int off = 1; off < 16; off <<= 1) {
        #pragma unroll
        for (int b = 0; b < 16; ++b) {
            float ob = __shfl_xor(best[b], off, 64);
            int   oi = __shfl_xor(bidx[b], off, 64);
            if (ob < best[b] || (ob == best[b] && oi < bidx[b])) {
                best[b] = ob; bidx[b] = oi;
            }
        }
    }

    // fold waves wn>=4 into wn<4 via (now dead) A-LDS, keeping NSLICE=16
    float2* fold = (float2*)AhL;        // 4 waves x 64 rows x float2 = 2 KB
    __syncthreads();                    // everyone done reading A
    if (wn >= 4 && (lane & 15) == 0) {
        #pragma unroll
        for (int mi = 0; mi < 4; ++mi)
            #pragma unroll
            for (int r = 0; r < 4; ++r) {
                int row = mi * 16 + (lane >> 4) * 4 + r;
                fold[(wn - 4) * 64 + row] =
                    make_float2(best[mi * 4 + r], (float)bidx[mi * 4 + r]);
            }
    }
    __syncthreads();
    if (wn < 4 && (lane & 15) == 0) {
        const size_t sl = (size_t)(slice * 4 + wn) * T_TOTAL;  // disjoint per (slice, wn)
        #pragma unroll
        for (int mi = 0; mi < 4; ++mi)
            #pragma unroll
            for (int r = 0; r < 4; ++r) {
                int row = mi * 16 + (lane >> 4) * 4 + r;
                int b = mi * 4 + r;
                float2 p = fold[wn * 64 + row];
                int pi = (int)p.y;
                if (p.x < best[b] || (p.x == best[b] && pi < bidx[b])) {
                    best[b] = p.x; bidx[b] = pi;
                }
                partial[sl + q0 + row] = make_float2(best[b], (float)bidx[b]);
            }
    }
}

// ---- kernel 3a (fused, needs partial in ws): fold 16 slices + gather, wave per row ----
__global__ void redgather_kernel(const float* __restrict__ vocab,
                                 const float2* __restrict__ partial,
                                 float* __restrict__ out) {
    int r    = blockIdx.x * 4 + (threadIdx.x >> 6);
    int lane = threadIdx.x & 63;
    float bm = 3.4e38f;
    int   bi = 0x7fffffff;
    if (lane < 16) {
        float2 p = partial[(size_t)lane * T_TOTAL + r];
        bm = p.x; bi = (int)p.y;
    }
    #pragma unroll
    for (int off = 1; off < 16; off <<= 1) {   // xor<16 stays within the 16-lane group
        float ob = __shfl_xor(bm, off, 64);
        int   oi = __shfl_xor(bi, off, 64);
        if (ob < bm || (ob == bm && oi < bi)) { bm = ob; bi = oi; }
    }
    int k = __shfl(bi, 0, 64);                 // lanes 0-15 hold the true min; take lane 0
    const float4* src = (const float4*)(vocab + (size_t)k * D);
    float4*       dst = (float4*)(out + (size_t)r * D);
    dst[lane] = src[lane];
    if (lane == 0) out[(size_t)T_TOTAL * D + r] = (float)k;
}

// ---- kernel 3b/4b (fallback path, partial at d_out head): separate reduce + gather ----
__global__ void reduce_kernel(const float2* __restrict__ partial, int* __restrict__ idx) {
    int q = blockIdx.x * 256 + threadIdx.x;
    float bm = 3.4e38f;
    int   bi = 0x7fffffff;
    #pragma unroll
    for (int s = 0; s < NSLICE; ++s) {
        float2 p = partial[(size_t)s * T_TOTAL + q];
        int pi = (int)p.y;
        if (p.x < bm || (p.x == bm && pi < bi)) { bm = p.x; bi = pi; }
    }
    idx[q] = bi;
}

__global__ void gather_kernel(const float* __restrict__ vocab,
                              const int* __restrict__ idx,
                              float* __restrict__ out) {
    int r    = blockIdx.x * 4 + (threadIdx.x >> 6);
    int lane = threadIdx.x & 63;
    int k = idx[r];
    const float4* src = (const float4*)(vocab + (size_t)k * D);
    float4*       dst = (float4*)(out + (size_t)r * D);
    dst[lane] = src[lane];
    if (lane == 0) out[(size_t)T_TOTAL * D + r] = (float)k;
}

extern "C" void kernel_launch(void* const* d_in, const int* in_sizes, int n_in,
                              void* d_out, int out_size, void* d_ws, size_t ws_size,
                              hipStream_t stream) {
    const float* seq   = (const float*)d_in[0];   // [T, D] f32
    const float* vocab = (const float*)d_in[1];   // [K, D] f32
    float* out = (float*)d_out;

    float* hv2 = (float*)d_ws;                               // K floats
    _Float16* bhi = (_Float16*)(out + PARTIAL_F);            // 4 MB (d_out scratch)
    _Float16* blo = bhi + BHALVES;                           // 4 MB

    // partial placement: ws if it fits (enables fused reduce+gather — no cross-kernel
    // race since gather never writes ws), else d_out head (R12 2-kernel path).
    const size_t need_ws = (size_t)(K + 2 * NSLICE * T_TOTAL) * sizeof(float) + 256;
    const bool fused = ws_size >= need_ws;

    hipLaunchKernelGGL(prep_kernel, dim3(NCT), dim3(256), 0, stream, vocab, bhi, blo, hv2);

    if (fused) {
        float2* partial = (float2*)(hv2 + K);                // in ws
        hipLaunchKernelGGL(argmin_kernel,    dim3(NQB * KSPLIT), dim3(512), 0, stream,
                           seq, bhi, blo, hv2, partial);
        hipLaunchKernelGGL(redgather_kernel, dim3(T_TOTAL / 4),  dim3(256), 0, stream,
                           vocab, partial, out);
    } else {
        float2* partial = (float2*)d_out;                    // at d_out head
        int* idx = (int*)(hv2 + K);                          // T ints in ws
        hipLaunchKernelGGL(argmin_kernel, dim3(NQB * KSPLIT), dim3(512), 0, stream,
                           seq, bhi, blo, hv2, partial);
        hipLaunchKernelGGL(reduce_kernel, dim3(T_TOTAL / 256), dim3(256), 0, stream, partial, idx);
        hipLaunchKernelGGL(gather_kernel, dim3(T_TOTAL / 4),   dim3(256), 0, stream, vocab, idx, out);
    }
}

// Round 10
// 425.673 us; speedup vs baseline: 7.2017x; 1.0913x over previous
//
#include <hip/hip_runtime.h>

// Problem constants: N=512, BS=64, DIM=256, SIZE=8192
#define T_TOTAL 32768   // N*BS queries
#define D       256
#define K       8192
#define BQ      64      // queries per block tile (4 row-tiles of 16) — shared by all 8 waves
#define KSPLIT  4
#define KSLICE  (K / KSPLIT)
#define NSLICE  (KSPLIT * 4)        // (slice, wn<4) pairs write disjoint partial slices
#define NCT     (K / 16)            // 512 code-tiles
#define KT_STRIDE (NCT * 64 * 8)    // halves per kt plane = 262144
#define NQB     (T_TOTAL / BQ)      // 512 query-blocks

typedef _Float16 half4f  __attribute__((ext_vector_type(4)));
typedef _Float16 half8f  __attribute__((ext_vector_type(8)));
typedef float    floatx4 __attribute__((ext_vector_type(4)));

// d_out scratch: Bhi/Blo after the first PARTIAL_F floats. If ws is big enough,
// partial lives in ws (enables fused reduce+gather); else at d_out head (R12 path).
#define PARTIAL_F 1048576
#define BHALVES   2097152   // halves per B array (8*512*64*8)

__device__ __forceinline__ _Float16 hi16(float x) { return (_Float16)x; }
__device__ __forceinline__ _Float16 lo16(float x, _Float16 h) { return (_Float16)(x - (float)h); }
__device__ __forceinline__ void split4(float4 v, half4f& h, half4f& l) {
    _Float16 hx = hi16(v.x), hy = hi16(v.y), hz = hi16(v.z), hw = hi16(v.w);
    h = (half4f){hx, hy, hz, hw};
    l = (half4f){lo16(v.x, hx), lo16(v.y, hy), lo16(v.z, hz), lo16(v.w, hw)};
}

// ---- kernel 1: fused vocab prep: hv2 (fp32-exact) + NEGATED fp16 hi/lo split ----
// R10: B is stored negated so the MFMA accumulates -dot; with acc initialized to
// 0.5|v|^2 the accumulator IS the score (kills 32 epilogue subs per tile per wave).
// hv2 itself uses the original v (sign-invariant). gather uses original vocab.
__global__ void prep_kernel(const float* __restrict__ vocab,
                            _Float16* __restrict__ bhi, _Float16* __restrict__ blo,
                            float* __restrict__ hv2) {
    const int ct = blockIdx.x;
    const int t  = threadIdx.x;
    const int k4 = t & 63;               // float4 index along D
    const int w  = t >> 6;
    const float4* voc4 = (const float4*)vocab;
    const int kt = k4 >> 3, kg = (k4 >> 1) & 3, h = k4 & 1;
    float ss[4];
    #pragma unroll
    for (int ci = 0; ci < 4; ++ci) {
        int cc = w * 4 + ci;             // code within tile
        float4 v = voc4[(size_t)(ct * 16 + cc) * (D / 4) + k4];
        ss[ci] = v.x * v.x + v.y * v.y + v.z * v.z + v.w * v.w;
        float4 nv = make_float4(-v.x, -v.y, -v.z, -v.w);
        half4f hh, ll;
        split4(nv, hh, ll);
        size_t off = (((size_t)kt * NCT + ct) * 64 + (cc + 16 * kg)) * 8 + h * 4;
        *(half4f*)&bhi[off] = hh;
        *(half4f*)&blo[off] = ll;
    }
    #pragma unroll
    for (int ci = 0; ci < 4; ++ci) {
        float s = ss[ci];
        #pragma unroll
        for (int off = 32; off; off >>= 1) s += __shfl_down(s, off, 64);
        if ((t & 63) == 0) hv2[ct * 16 + w * 4 + ci] = 0.5f * s;
    }
}

// ------ kernel 2: MFMA argmin; 3-term split; 8 code-split waves; VALU-diet schedule ----
// Model (R0-R9 consolidated): MFMA-busy is pinned at the ~200us per-SIMD floor in every
// clean run; VALU-busy ~130-170us; the two SUM to ~100% of duration (additive issue) —
// ILP/TLP restructuring never overlapped them (R9: prefetch at 4w/SIMD ADDED idle).
// R10 keeps the best skeleton (R6, no prefetch, issue-saturated) and cuts VALU count:
//  (1) walking B pointers (2 increments/kt + offset:1024 folding, not 4x 64-bit GEPs)
//  (2) LDS reads: ao = (mi*8+kt)*512 + (lane8 ^ kt<<3) -> 2 VALU/kt + immediates
//  (3) negated-B + hv-initialized acc: score = acc directly, no epilogue sub;
//      hv2 for tile i+1 loaded before tile i's epilogue (latency hidden)
//  (4) bidx kept packed (live regs ~120 <= 128 cap).
// Occupancy: __launch_bounds__(512,2) — R9-proven: 2 blocks/CU, 128-reg cap, no spill.
__launch_bounds__(512, 2)
__global__ void argmin_kernel(const float* __restrict__ seq,
                              const _Float16* __restrict__ bhi,
                              const _Float16* __restrict__ blo,
                              const float* __restrict__ hv2,
                              float2* __restrict__ partial) {
    // A LDS in fragment order [rt 0..3][kt 0..7][flane 0..63][8], XOR-swizzled by kt<<3
    __shared__ _Float16 AhL[4 * 8 * 64 * 8];   // 32 KB
    __shared__ _Float16 AlL[4 * 8 * 64 * 8];   // 32 KB

    const int t    = threadIdx.x;
    const int lane = t & 63;
    const int wn   = t >> 6;            // code octant 0..7 (32 codes each per c0 tile)
    const int bi   = blockIdx.x;
    const int slice = (bi & 7) >> 1;    // 0..3  (XCD-locked K-slice)
    const int qb    = (bi >> 3) * 2 + (bi & 1);  // 0..511
    const int q0   = qb * BQ;
    const int k0   = slice * KSLICE;

    const float4* seq4 = (const float4*)seq;

    // ---- prologue: split A (64 rows x 256 dims) into fragment-order LDS, once ----
    #pragma unroll
    for (int i = 0; i < 8; ++i) {
        int f   = t + 512 * i;          // 0..4095 float4s
        int row = f >> 6;               // 0..63
        int d4  = f & 63;               // float4 along D
        float4 v = seq4[(size_t)(q0 + row) * (D / 4) + d4];
        half4f h, l;
        split4(v, h, l);
        int kt = d4 >> 3, kg = (d4 >> 1) & 3, hh = d4 & 1;
        int off = (((((row >> 4) * 8 + kt) * 64) + ((row & 15) + 16 * kg)) * 8 + hh * 4)
                  ^ (kt << 3);          // swizzle: write conflicts 32-way -> 4-way
        *(half4f*)&AhL[off] = h;
        *(half4f*)&AlL[off] = l;
    }
    __syncthreads();

    float    best[16];
    unsigned bidxp[8];                  // 2x16-bit packed indices (K fits in 13 bits)
    #pragma unroll
    for (int b = 0; b < 16; ++b) best[b] = 3.4e38f;
    #pragma unroll
    for (int b = 0; b < 8; ++b) bidxp[b] = 0u;

    const int lane8 = lane << 3;
    const int cidx  = lane & 15;

    // walking B pointers: base = code-tile base + lane fragment offset
    const size_t cb0 = ((size_t)(k0 >> 4) + wn * 2) * 512;
    const _Float16* pbh = bhi + cb0 + lane8;
    const _Float16* pbl = blo + cb0 + lane8;

    // hv for tile 0 (one ~300cy stall, once); subsequent tiles prefetched pre-epilogue
    float hvn0 = hv2[k0 + (wn * 2 + 0) * 16 + cidx];
    float hvn1 = hv2[k0 + (wn * 2 + 1) * 16 + cidx];

    for (int c0i = 0; c0i < KSLICE / 256; ++c0i) {   // 8 c0 tiles of 256 codes
        const int c0 = k0 + c0i * 256;

        // acc initialized to 0.5|v|^2 (per-code, col = lane&15); B negated -> acc = score
        floatx4 acc[4][2];
        #pragma unroll
        for (int nj = 0; nj < 2; ++nj) {
            const float hv = nj ? hvn1 : hvn0;
            #pragma unroll
            for (int mi = 0; mi < 4; ++mi)
                acc[mi][nj] = (floatx4){hv, hv, hv, hv};
        }

        #pragma unroll 1   // REAL loop: bounded hoist window (anti-spill)
        for (int kt = 0; kt < 8; ++kt) {
            // B: 4 loads off 2 walking pointers (+512 halves folds into offset:1024)
            half8f bh[2], bl[2];
            bh[0] = *(const half8f*)pbh;
            bh[1] = *(const half8f*)(pbh + 512);
            bl[0] = *(const half8f*)pbl;
            bl[1] = *(const half8f*)(pbl + 512);
            pbh += KT_STRIDE;
            pbl += KT_STRIDE;
            // A: one XOR + one add; mi-term folds into ds_read immediates
            const int ak = (lane8 ^ (kt << 3)) + (kt << 9);
            half8f ah[4], al[4];
            #pragma unroll
            for (int mi = 0; mi < 4; ++mi) {
                al[mi] = *(const half8f*)&AlL[ak + mi * 4096];
                ah[mi] = *(const half8f*)&AhL[ak + mi * 4096];
            }
            // 24 MFMAs, term-outer: 8 independent accs between dependent pairs
            __builtin_amdgcn_s_setprio(1);
            #pragma unroll
            for (int nj = 0; nj < 2; ++nj)
                #pragma unroll
                for (int mi = 0; mi < 4; ++mi)
                    acc[mi][nj] = __builtin_amdgcn_mfma_f32_16x16x32_f16(al[mi], bh[nj], acc[mi][nj], 0, 0, 0);
            #pragma unroll
            for (int nj = 0; nj < 2; ++nj)
                #pragma unroll
                for (int mi = 0; mi < 4; ++mi)
                    acc[mi][nj] = __builtin_amdgcn_mfma_f32_16x16x32_f16(ah[mi], bl[nj], acc[mi][nj], 0, 0, 0);
            #pragma unroll
            for (int nj = 0; nj < 2; ++nj)
                #pragma unroll
                for (int mi = 0; mi < 4; ++mi)
                    acc[mi][nj] = __builtin_amdgcn_mfma_f32_16x16x32_f16(ah[mi], bh[nj], acc[mi][nj], 0, 0, 0);
            __builtin_amdgcn_s_setprio(0);
        }
        // rewind pointers to the next c0 tile (tile stride = 16 code-tiles x 512)
        pbh += 8192 - 8 * (size_t)KT_STRIDE;
        pbl += 8192 - 8 * (size_t)KT_STRIDE;

        // prefetch next tile's hv BEFORE the epilogue (epilogue hides the latency)
        if (c0i < KSLICE / 256 - 1) {
            hvn0 = hv2[c0 + 256 + (wn * 2 + 0) * 16 + cidx];
            hvn1 = hv2[c0 + 256 + (wn * 2 + 1) * 16 + cidx];
        }

        // epilogue: acc IS the score; running first-argmin (ascending c per lane).
        // C/D layout: col = lane&15, row = (lane>>4)*4 + reg
        #pragma unroll
        for (int nj = 0; nj < 2; ++nj) {
            const int c = c0 + (wn * 2 + nj) * 16 + cidx;
            const unsigned clo = (unsigned)c;
            const unsigned chi = (unsigned)c << 16;
            #pragma unroll
            for (int mi = 0; mi < 4; ++mi)
                #pragma unroll
                for (int r = 0; r < 4; r += 2) {
                    const int b = mi * 4 + r;
                    float s0 = acc[mi][nj][r];
                    float s1 = acc[mi][nj][r + 1];
                    unsigned w = bidxp[b >> 1];
                    if (s0 < best[b])     { best[b] = s0;     w = (w & 0xFFFF0000u) | clo; }
                    if (s1 < best[b + 1]) { best[b + 1] = s1; w = (w & 0x0000FFFFu) | chi; }
                    bidxp[b >> 1] = w;
                }
        }
    }

    // unpack indices (registers are cheap after the hot loop)
    int bidx[16];
    #pragma unroll
    for (int b = 0; b < 16; ++b)
        bidx[b] = (b & 1) ? (int)(bidxp[b >> 1] >> 16) : (int)(bidxp[b >> 1] & 0xFFFFu);

    // reduce across the 16 col-lanes (same rows, 16 different cols)
    #pragma unroll
    for (int off = 1; off < 16; off <<= 1) {
        #pragma unroll
        for (int b = 0; b < 16; ++b) {
            float ob = __shfl_xor(best[b], off, 64);
            int   oi = __shfl_xor(bidx[b], off, 64);
            if (ob < best[b] || (ob == best[b] && oi < bidx[b])) {
                best[b] = ob; bidx[b] = oi;
            }
        }
    }

    // fold waves wn>=4 into wn<4 via (now dead) A-LDS, keeping NSLICE=16
    float2* fold = (float2*)AhL;        // 4 waves x 64 rows x float2 = 2 KB
    __syncthreads();                    // everyone done reading A
    if (wn >= 4 && (lane & 15) == 0) {
        #pragma unroll
        for (int mi = 0; mi < 4; ++mi)
            #pragma unroll
            for (int r = 0; r < 4; ++r) {
                int row = mi * 16 + (lane >> 4) * 4 + r;
                fold[(wn - 4) * 64 + row] =
                    make_float2(best[mi * 4 + r], (float)bidx[mi * 4 + r]);
            }
    }
    __syncthreads();
    if (wn < 4 && (lane & 15) == 0) {
        const size_t sl = (size_t)(slice * 4 + wn) * T_TOTAL;  // disjoint per (slice, wn)
        #pragma unroll
        for (int mi = 0; mi < 4; ++mi)
            #pragma unroll
            for (int r = 0; r < 4; ++r) {
                int row = mi * 16 + (lane >> 4) * 4 + r;
                int b = mi * 4 + r;
                float2 p = fold[wn * 64 + row];
                int pi = (int)p.y;
                if (p.x < best[b] || (p.x == best[b] && pi < bidx[b])) {
                    best[b] = p.x; bidx[b] = pi;
                }
                partial[sl + q0 + row] = make_float2(best[b], (float)bidx[b]);
            }
    }
}

// ---- kernel 3a (fused, needs partial in ws): fold 16 slices + gather, wave per row ----
__global__ void redgather_kernel(const float* __restrict__ vocab,
                                 const float2* __restrict__ partial,
                                 float* __restrict__ out) {
    int r    = blockIdx.x * 4 + (threadIdx.x >> 6);
    int lane = threadIdx.x & 63;
    float bm = 3.4e38f;
    int   bi = 0x7fffffff;
    if (lane < 16) {
        float2 p = partial[(size_t)lane * T_TOTAL + r];
        bm = p.x; bi = (int)p.y;
    }
    #pragma unroll
    for (int off = 1; off < 16; off <<= 1) {   // xor<16 stays within the 16-lane group
        float ob = __shfl_xor(bm, off, 64);
        int   oi = __shfl_xor(bi, off, 64);
        if (ob < bm || (ob == bm && oi < bi)) { bm = ob; bi = oi; }
    }
    int k = __shfl(bi, 0, 64);                 // lanes 0-15 hold the true min; take lane 0
    const float4* src = (const float4*)(vocab + (size_t)k * D);
    float4*       dst = (float4*)(out + (size_t)r * D);
    dst[lane] = src[lane];
    if (lane == 0) out[(size_t)T_TOTAL * D + r] = (float)k;
}

// ---- kernel 3b/4b (fallback path, partial at d_out head): separate reduce + gather ----
__global__ void reduce_kernel(const float2* __restrict__ partial, int* __restrict__ idx) {
    int q = blockIdx.x * 256 + threadIdx.x;
    float bm = 3.4e38f;
    int   bi = 0x7fffffff;
    #pragma unroll
    for (int s = 0; s < NSLICE; ++s) {
        float2 p = partial[(size_t)s * T_TOTAL + q];
        int pi = (int)p.y;
        if (p.x < bm || (p.x == bm && pi < bi)) { bm = p.x; bi = pi; }
    }
    idx[q] = bi;
}

__global__ void gather_kernel(const float* __restrict__ vocab,
                              const int* __restrict__ idx,
                              float* __restrict__ out) {
    int r    = blockIdx.x * 4 + (threadIdx.x >> 6);
    int lane = threadIdx.x & 63;
    int k = idx[r];
    const float4* src = (const float4*)(vocab + (size_t)k * D);
    float4*       dst = (float4*)(out + (size_t)r * D);
    dst[lane] = src[lane];
    if (lane == 0) out[(size_t)T_TOTAL * D + r] = (float)k;
}

extern "C" void kernel_launch(void* const* d_in, const int* in_sizes, int n_in,
                              void* d_out, int out_size, void* d_ws, size_t ws_size,
                              hipStream_t stream) {
    const float* seq   = (const float*)d_in[0];   // [T, D] f32
    const float* vocab = (const float*)d_in[1];   // [K, D] f32
    float* out = (float*)d_out;

    float* hv2 = (float*)d_ws;                               // K floats
    _Float16* bhi = (_Float16*)(out + PARTIAL_F);            // 4 MB (d_out scratch)
    _Float16* blo = bhi + BHALVES;                           // 4 MB

    // partial placement: ws if it fits (enables fused reduce+gather — no cross-kernel
    // race since gather never writes ws), else d_out head (R12 2-kernel path).
    const size_t need_ws = (size_t)(K + 2 * NSLICE * T_TOTAL) * sizeof(float) + 256;
    const bool fused = ws_size >= need_ws;

    hipLaunchKernelGGL(prep_kernel, dim3(NCT), dim3(256), 0, stream, vocab, bhi, blo, hv2);

    if (fused) {
        float2* partial = (float2*)(hv2 + K);                // in ws
        hipLaunchKernelGGL(argmin_kernel,    dim3(NQB * KSPLIT), dim3(512), 0, stream,
                           seq, bhi, blo, hv2, partial);
        hipLaunchKernelGGL(redgather_kernel, dim3(T_TOTAL / 4),  dim3(256), 0, stream,
                           vocab, partial, out);
    } else {
        float2* partial = (float2*)d_out;                    // at d_out head
        int* idx = (int*)(hv2 + K);                          // T ints in ws
        hipLaunchKernelGGL(argmin_kernel, dim3(NQB * KSPLIT), dim3(512), 0, stream,
                           seq, bhi, blo, hv2, partial);
        hipLaunchKernelGGL(reduce_kernel, dim3(T_TOTAL / 256), dim3(256), 0, stream, partial, idx);
        hipLaunchKernelGGL(gather_kernel, dim3(T_TOTAL / 4),   dim3(256), 0, stream, vocab, idx, out);
    }
}